// Round 3
// baseline (474.006 us; speedup 1.0000x reference)
//
#include <hip/hip_runtime.h>

typedef unsigned short ushort_t;
typedef unsigned int   uint_t;
typedef __attribute__((ext_vector_type(8))) short  short8;
typedef __attribute__((ext_vector_type(4))) float  float4v;
typedef __attribute__((ext_vector_type(4))) uint_t uint4v;

#define B_    16
#define CIN_  320
#define COUT_ 320
#define NLORA 50
#define R_    4

// workspace layout (bytes)
#define XPAD_ELEMS ((size_t)B_ * 66 * 66 * CIN_)        // bf16 NHWC padded x
#define WB_OFF     (XPAD_ELEMS * 2)                     // base weights bf16 [9][320][320]
#define DB_OFF     (WB_OFF + (size_t)9 * 320 * 320 * 2) // per-b down bf16 [16][9][4][320]

__device__ __forceinline__ ushort_t bf16rne(float f) {
  uint_t u = __float_as_uint(f);
  u = (u + 0x7FFFu + ((u >> 16) & 1u)) >> 16;
  return (ushort_t)u;
}

#define GLDS16(gp, lp)                                                          \
  __builtin_amdgcn_global_load_lds(                                             \
      (const __attribute__((address_space(1))) void*)(gp),                      \
      (__attribute__((address_space(3))) void*)(lp), 16, 0, 0)

// lora_id int32/int64 detect + decode (first 64 B valid under either dtype)
__device__ __forceinline__ void lora_decode(const void* lora, int b, int* l_out,
                                            float* act_out) {
  const int* p32 = (const int*)lora;
  bool odd0 = true;
  #pragma unroll
  for (int i = 1; i < 16; i += 2) odd0 = odd0 && (p32[i] == 0);
  long long raw = odd0 ? ((const long long*)lora)[b] : (long long)p32[b];
  long long idx = (raw >= 0) ? (raw >> 2) : -(((-raw) + 3) >> 2);   // floor/4
  *act_out = (idx >= 0) ? 1.0f : 0.0f;                              // SCALE==1 folded
  *l_out = (int)(idx < 0 ? 0 : (idx > (NLORA - 1) ? (NLORA - 1) : idx));
}

// ---------------------------------------------------------------------------
// Kernel 0: zero the 1-px halo of x_pad (2.66 MB).
// ---------------------------------------------------------------------------
__global__ __launch_bounds__(256)
void zero_borders(ushort_t* __restrict__ x_pad) {
  int g = blockIdx.x * 256 + threadIdx.x;        // 0 .. 166399
  int b = g / 10400;
  int r = g - b * 10400;
  int cell = r / 40;
  int v = r - cell * 40;
  int hh, ww;
  if (cell < 66)       { hh = 0;          ww = cell; }
  else if (cell < 132) { hh = 65;         ww = cell - 66; }
  else if (cell < 196) { hh = cell - 131; ww = 0; }
  else                 { hh = cell - 195; ww = 65; }
  *(uint4v*)(x_pad + (((size_t)(b * 66 + hh)) * 66 + ww) * CIN_ + v * 8) = (uint4v)0u;
}

// ---------------------------------------------------------------------------
// Kernel 1: x [B][C][H][W] fp32 -> x_pad [B][66][66][C] bf16 (interior).
// ---------------------------------------------------------------------------
__global__ __launch_bounds__(256)
void pad_convert(const float* __restrict__ x, ushort_t* __restrict__ x_pad) {
  __shared__ float t[64][65];
  const int cc  = blockIdx.x;   // channel chunk 0..4
  const int h   = blockIdx.y;   // 0..63
  const int b   = blockIdx.z;
  const int tid = threadIdx.x;
  #pragma unroll
  for (int it = 0; it < 4; ++it) {
    int g  = it * 256 + tid;
    int cl = g >> 4, w4 = (g & 15) * 4;
    float4v v = *(const float4v*)(x +
        (((size_t)(b * CIN_ + cc * 64 + cl)) * 64 + h) * 64 + w4);
    t[cl][w4 + 0] = v.x; t[cl][w4 + 1] = v.y;
    t[cl][w4 + 2] = v.z; t[cl][w4 + 3] = v.w;
  }
  __syncthreads();
  #pragma unroll
  for (int it = 0; it < 2; ++it) {
    int g   = it * 256 + tid;
    int ch8 = g & 7;
    int w   = g >> 3;
    uint4v p;
    p.x = (uint_t)bf16rne(t[ch8 * 8 + 0][w]) | ((uint_t)bf16rne(t[ch8 * 8 + 1][w]) << 16);
    p.y = (uint_t)bf16rne(t[ch8 * 8 + 2][w]) | ((uint_t)bf16rne(t[ch8 * 8 + 3][w]) << 16);
    p.z = (uint_t)bf16rne(t[ch8 * 8 + 4][w]) | ((uint_t)bf16rne(t[ch8 * 8 + 5][w]) << 16);
    p.w = (uint_t)bf16rne(t[ch8 * 8 + 6][w]) | ((uint_t)bf16rne(t[ch8 * 8 + 7][w]) << 16);
    *(uint4v*)(x_pad + (((size_t)(b * 66 + h + 1)) * 66 + (w + 1)) * CIN_ + cc * 64 + ch8 * 8) = p;
  }
}

// ---------------------------------------------------------------------------
// Kernel 2: base conv weights -> bf16, layout Wb[tap][o][c]  (b-independent).
// ---------------------------------------------------------------------------
__global__ __launch_bounds__(320)
void wconv(const float* __restrict__ conv_w, ushort_t* __restrict__ Wb) {
  __shared__ __align__(16) float lw[2880];
  const int o = blockIdx.x, c = threadIdx.x;
  const float4v* src = (const float4v*)(conv_w + (size_t)o * 2880);
  for (int g = c; g < 720; g += 320) ((float4v*)lw)[g] = src[g];
  __syncthreads();
  #pragma unroll
  for (int tap = 0; tap < 9; ++tap)
    Wb[((size_t)tap * COUT_ + o) * CIN_ + c] = bf16rne(lw[c * 9 + tap]);
}

// ---------------------------------------------------------------------------
// Kernel 3: gathered per-sample down weights -> bf16, Db[b][tap][r][c].
// ---------------------------------------------------------------------------
__global__ __launch_bounds__(320)
void dconv(const float* __restrict__ down_w, const void* __restrict__ lora,
           ushort_t* __restrict__ Db) {
  const int b = blockIdx.x, c = threadIdx.x;
  int l; float act;
  lora_decode(lora, b, &l, &act);
  #pragma unroll
  for (int r = 0; r < R_; ++r)
    #pragma unroll
    for (int tap = 0; tap < 9; ++tap)
      Db[(((size_t)b * 9 + tap) * R_ + r) * CIN_ + c] =
          bf16rne(down_w[(size_t)l * 11520 + r * 2880 + c * 9 + tap]);
}

// ---------------------------------------------------------------------------
// Kernel 4: fused implicit-GEMM conv + in-loop rank-4 down-proj MFMA.
// 512 thr (8 waves). Tile M=512 (8 rows x 64 cols), N=64 base + 4 down cols.
// XCD-aware decode: blockIdx.x & 7 = XCD -> 2 b's per XCD (x resident in L2);
// Wb (1.84 MB) L2-resident everywhere.
// ---------------------------------------------------------------------------
__global__ __launch_bounds__(512, 4)
void conv_main(const ushort_t* __restrict__ x_pad, const ushort_t* __restrict__ Wb,
               const ushort_t* __restrict__ Db, const float* __restrict__ conv_b,
               const float* __restrict__ up_w, const void* __restrict__ lora,
               float* __restrict__ out) {
  __shared__ __align__(16) char smem[81472];
  ushort_t* xs = (ushort_t*)smem;             // [10][66][4 slot][8ch] 42240 B
  ushort_t* wt = (ushort_t*)(smem + 42240);   // [9][64][4 slot][8ch] 36864 B
  ushort_t* wd = (ushort_t*)(smem + 79104);   // [9][4 r][4 slot][8ch] 2304 B
  ushort_t* zz = (ushort_t*)(smem + 81408);   // 64 B zeros
  float*    lc = (float*)smem;                // epilogue [32][516] fp32 66048 B

  const int tid = threadIdx.x;
  // XCD-aware work decode
  const int id   = blockIdx.x;        // 0..639
  const int xcd  = id & 7;
  const int slot = id >> 3;           // 0..79
  const int b    = xcd * 2 + (slot >= 40);
  const int s2   = (slot >= 40) ? slot - 40 : slot;
  const int o0   = (s2 >> 3) * 64;
  const int h0   = (s2 & 7) * 8;

  const int wv = tid >> 6;            // wave -> output row h0+wv
  const int la = tid & 15;
  const int q  = (tid >> 4) & 3;

  if (tid < 4) ((uint4v*)zz)[tid] = (uint4v)0u;

  // staging source offsets (elements, sans c0)
  int xoff[6];
  #pragma unroll
  for (int it = 0; it < 6; ++it) {
    int g  = tid + it * 512;
    int hh = g / 264;
    int r  = g - hh * 264;
    int ww = r >> 2;
    int s  = r & 3;
    xoff[it] = ((b * 66 + h0 + hh) * 66 + ww) * CIN_ + (((s ^ (ww >> 1)) & 3) * 8);
  }
  int woff[5];
  #pragma unroll
  for (int it = 0; it < 5; ++it) {
    int g   = tid + it * 512;
    int tap = g >> 8;
    int o   = (g >> 2) & 63;
    int s   = g & 3;
    woff[it] = (tap * COUT_ + o0 + o) * CIN_ + (((s ^ (o >> 1)) & 3) * 8);
  }
  int dwoff = 0;
  if (tid < 144)
    dwoff = (((b * 9 + (tid >> 4)) * R_) + ((tid >> 2) & 3)) * CIN_ + (tid & 3) * 8;

  float4v acc[4][4];
  float4v acc_d[4];
  #pragma unroll
  for (int i = 0; i < 4; ++i) {
    acc_d[i] = (float4v)0.0f;
    #pragma unroll
    for (int n = 0; n < 4; ++n) acc[i][n] = (float4v)0.0f;
  }

  for (int c0 = 0; c0 < CIN_; c0 += 32) {
    __syncthreads();
    #pragma unroll
    for (int it = 0; it < 6; ++it) {
      int g = tid + it * 512;
      if (it < 5 || g < 2640) GLDS16(x_pad + xoff[it] + c0, xs + g * 8);
    }
    #pragma unroll
    for (int it = 0; it < 5; ++it) {
      int g = tid + it * 512;
      if (it < 4 || g < 2304) GLDS16(Wb + woff[it] + c0, wt + g * 8);
    }
    if (tid < 144) GLDS16(Db + dwoff + c0, wd + tid * 8);
    __syncthreads();

    #pragma unroll
    for (int tap = 0; tap < 9; ++tap) {
      const int kh = tap / 3, kw = tap % 3;
      short8 bf[4];
      #pragma unroll
      for (int n = 0; n < 4; ++n) {
        int o = n * 16 + la;
        bf[n] = *(const short8*)(wt + ((tap * 64 + o) * 4 + ((q ^ (o >> 1)) & 3)) * 8);
      }
      short8 bd = (la < 4) ? *(const short8*)(wd + ((tap * 4 + la) * 4 + q) * 8)
                           : *(const short8*)zz;
      const int hh = wv + kh;
      #pragma unroll
      for (int i = 0; i < 4; ++i) {
        int ww = i * 16 + la + kw;
        short8 af = *(const short8*)(xs + ((hh * 66 + ww) * 4 + ((q ^ (ww >> 1)) & 3)) * 8);
        #pragma unroll
        for (int n = 0; n < 4; ++n)
          acc[i][n] = __builtin_amdgcn_mfma_f32_16x16x32_bf16(af, bf[n], acc[i][n], 0, 0, 0);
        acc_d[i] = __builtin_amdgcn_mfma_f32_16x16x32_bf16(af, bd, acc_d[i], 0, 0, 0);
      }
    }
  }

  // ---- LoRA epilogue: acc += up[o,r] * down_acc[r] (cross-lane gather)
  int l; float act;
  lora_decode(lora, b, &l, &act);
  float4v upv[4];
  #pragma unroll
  for (int n = 0; n < 4; ++n) {
    int o = o0 + n * 16 + la;
    upv[n] = act * (*(const float4v*)(up_w + ((size_t)l * COUT_ + o) * R_));
  }
  #pragma unroll
  for (int i = 0; i < 4; ++i) {
    float yd[4][4];   // [r][reg]
    #pragma unroll
    for (int rp = 0; rp < 4; ++rp)
      #pragma unroll
      for (int r = 0; r < 4; ++r)
        yd[r][rp] = __shfl(acc_d[i][rp], (q << 4) + r, 64);
    #pragma unroll
    for (int n = 0; n < 4; ++n)
      #pragma unroll
      for (int rp = 0; rp < 4; ++rp)
        acc[i][n][rp] += upv[n].x * yd[0][rp] + upv[n].y * yd[1][rp]
                       + upv[n].z * yd[2][rp] + upv[n].w * yd[3][rp];
  }

  // ---- Epilogue: LDS transpose -> coalesced full-line NCHW stores + bias
  #pragma unroll
  for (int half = 0; half < 2; ++half) {
    __syncthreads();
    #pragma unroll
    for (int nn = 0; nn < 2; ++nn) {
      const int n = half * 2 + nn;
      const int o_loc = nn * 16 + la;
      #pragma unroll
      for (int i = 0; i < 4; ++i) {
        const int m = wv * 64 + i * 16 + q * 4;
        *(float4v*)(lc + o_loc * 516 + m) = acc[i][n];
      }
    }
    __syncthreads();
    #pragma unroll
    for (int it = 0; it < 8; ++it) {
      int f = tid + it * 512;          // 0..4095
      int o_loc = f >> 7;              // 0..31
      int m4 = (f & 127) * 4;          // 0..508
      int row = m4 >> 6, col = m4 & 63;
      int o = o0 + half * 32 + o_loc;
      float4v v = *(const float4v*)(lc + o_loc * 516 + m4);
      v += conv_b[o];
      *(float4v*)(out + (((size_t)b * COUT_ + o) * 64 + h0 + row) * 64 + col) = v;
    }
  }
}

// ---------------------------------------------------------------------------
extern "C" void kernel_launch(void* const* d_in, const int* in_sizes, int n_in,
                              void* d_out, int out_size, void* d_ws, size_t ws_size,
                              hipStream_t stream) {
  const float* x      = (const float*)d_in[0];
  const float* conv_w = (const float*)d_in[1];
  const float* conv_b = (const float*)d_in[2];
  const float* down_w = (const float*)d_in[3];
  const float* up_w   = (const float*)d_in[4];
  const void*  lora   = d_in[5];
  float* out = (float*)d_out;

  ushort_t* x_pad = (ushort_t*)d_ws;
  ushort_t* Wb    = (ushort_t*)((char*)d_ws + WB_OFF);
  ushort_t* Db    = (ushort_t*)((char*)d_ws + DB_OFF);

  zero_borders <<<dim3(650),        256, 0, stream>>>(x_pad);
  pad_convert  <<<dim3(5, 64, 16),  256, 0, stream>>>(x, x_pad);
  wconv        <<<dim3(320),        320, 0, stream>>>(conv_w, Wb);
  dconv        <<<dim3(16),         320, 0, stream>>>(down_w, lora, Db);
  conv_main    <<<dim3(640),        512, 0, stream>>>(x_pad, Wb, Db, conv_b,
                                                      up_w, lora, out);
}